// Round 6
// baseline (210.144 us; speedup 1.0000x reference)
//
#include <hip/hip_runtime.h>

#define NSTEP 2047
#define NB    4096

__device__ __forceinline__ float fexp2(float x) {
    float r; asm("v_exp_f32 %0, %1" : "=v"(r) : "v"(x)); return r;
}
__device__ __forceinline__ float frcp(float x) {
    float r; asm("v_rcp_f32 %0, %1" : "=v"(r) : "v"(x)); return r;
}
// quad_perm DPP: lane l reads lane sel[l] of its quad. CTRL = p0|p1<<2|p2<<4|p3<<6.
template <int CTRL>
__device__ __forceinline__ float qperm(float x) {
    int i = __builtin_bit_cast(int, x);
    i = __builtin_amdgcn_mov_dpp(i, CTRL, 0xF, 0xF, true);
    return __builtin_bit_cast(float, i);
}
#define XOR1 0xB1  // [1,0,3,2]
#define XOR2 0x4E  // [2,3,0,1]
#define ROT1 0x39  // [1,2,3,0] : lane l <- l+1
#define ROT3 0x93  // [3,0,1,2] : lane l <- l-1

__global__ __launch_bounds__(64, 1)
void cstr_kernel(const float* __restrict__ w, const float* __restrict__ Kp,
                 const float* __restrict__ Lp, const float* __restrict__ Mp,
                 const float* __restrict__ Mop, float* __restrict__ out)
{
    const int tid = blockIdx.x * 64 + threadIdx.x;   // 0..16383
    const int q   = tid & 3;                         // quad lane: owns rx[q]
    const int b   = tid >> 2;                        // sample

    constexpr float Hc  = 0.01f;
    constexpr float Acf = 1.0f - Hc;
    constexpr float Bcf = -0.5f * Hc * Hc;
    constexpr float T2L = 2.8853900817779268f;  // 2*log2(e)
    constexpr float L2E = 1.4426950408889634f;  // log2(e)
    constexpr float SC1 = 0.5f * Hc;            // H/2 tanh shift
    constexpr float HH  = 0.5f * Hc;

    const float K0 = Kp[0], K1 = Kp[1], MoV = Mop[0];

    // symmetrized A = (L+L^T)/2, scalar names (compile-time indexed only)
    const float A00 = Lp[0], A11 = Lp[5], A22 = Lp[10], A33 = Lp[15];
    const float A01 = 0.5f * (Lp[1]  + Lp[4]);
    const float A02 = 0.5f * (Lp[2]  + Lp[8]);
    const float A03 = 0.5f * (Lp[3]  + Lp[12]);
    const float A12 = 0.5f * (Lp[6]  + Lp[9]);
    const float A13 = 0.5f * (Lp[7]  + Lp[13]);
    const float A23 = 0.5f * (Lp[11] + Lp[14]);

    const bool odd = (q & 1) != 0;
    const bool hi  = (q & 2) != 0;
    // ---- per-lane constants (then laundered into pinned VGPRs) ----
    float cTf    = odd ? -Hc : Hc;         // coeff of partner tanh
    float cUf    = odd ? HH  : Hc;         // coeff of u
    float c0f    = odd ? Bcf : 0.0f;       // additive const in f-row
    float shiftc = odd ? SC1 * T2L : 0.0f; // pre-scaled tanh shift
    float cKn    = (q == 2) ? K0 : (q == 3) ? K1 : 0.0f;
    float cwc    = (q == 1) ? Bcf : 0.0f;  // Bcf for the x2-row x update
    // phi row coeffs: h_q = am + a0*V + a1*rot1 + a2*rot2 + a3*rot3
    float am = (q == 0) ? Mp[0] : (q == 1) ? Mp[1] : (q == 2) ? Mp[2] : Mp[3];
    float a0 = (q == 0) ? A00 : (q == 1) ? A11 : (q == 2) ? A22 : A33;
    float a1 = (q == 0) ? A01 : (q == 1) ? A12 : (q == 2) ? A23 : A03;
    float a2 = (q == 0) ? A02 : (q == 1) ? A13 : (q == 2) ? A02 : A13;
    float a3 = (q == 0) ? A03 : (q == 1) ? A01 : (q == 2) ? A12 : A23;
    float sigBias = -MoV * L2E;            // uniform, but pin as VGPR (VOP3 literal rule)
    // Launder: make values opaque so the compiler keeps them resident in VGPRs
    // instead of rematerializing the select chains every step (r5: VGPR=20,
    // ~45 remat insts/step).
    asm volatile("" : "+v"(cTf), "+v"(cUf), "+v"(c0f), "+v"(shiftc),
                      "+v"(cKn), "+v"(cwc), "+v"(am), "+v"(a0),
                      "+v"(a1), "+v"(a2), "+v"(a3), "+v"(sigBias));

    const float* rw = w + (size_t)b * (2 * NSTEP) + (size_t)(q & 1) * NSTEP;
    const float w_0 = rw[0], w_1 = rw[1], w_T = rw[2046];

    // prologue tanh(1) and tanh(H/2)
    const float th1 = 1.0f - 2.0f * frcp(fexp2(T2L) + 1.0f);
    const float thS = 1.0f - 2.0f * frcp(fexp2(SC1 * T2L) + 1.0f);

    // ---- t = 0 (delta=1, xhat0=(1,0), u0=K0) -> state entering step t=1 ----
    // lanes 0,1 hold x(t=1); lanes 2,3 hold xhat(t=1) = x0 = (1,0)
    float St = (q == 0) ? (Acf + Hc * SC1 + Hc * K0 + w_0)
             : (q == 1) ? (Bcf - Hc * th1 + HH * K0 + w_0)
             : (q == 2) ? 1.0f : 0.0f;
    // swapped xhat-tanh entering step 1: lane2 needs S(xh2_0)=tanh(H/2), lane3 tanh(xh1_0)=tanh(1)
    float TPin = (q == 2) ? thS : (q == 3) ? th1 : 0.0f;
    float U   = K0;
    float SXX = (q == 0) ? 1.0f : 0.0f;   // lane0: sum x1^2 (incl t=0), lane1: sum x2^2
    float SXY = 0.0f;                     // lane0: sum x1*x2
    float SD  = 1.0f;                     // sum deltas (t=0 term = 1)

    auto step = [&](float wi, bool acc) {
        // F = f(xhat_prev, u_prev) component (valid on lanes 2,3)
        const float cc = __builtin_fmaf(cUf, U, c0f);
        const float F  = __builtin_fmaf(Acf, St, __builtin_fmaf(cTf, TPin, cc));
        // rx component: lanes 0,1 -> x ; lanes 2,3 -> F
        const float V  = hi ? F : St;
        // quad gather for phi row
        const float r1 = qperm<ROT1>(V);
        const float r2 = qperm<XOR2>(V);
        const float r3 = qperm<ROT3>(V);
        float h = __builtin_fmaf(a0, V, am);
        h = __builtin_fmaf(a1, r1, h);
        h = __builtin_fmaf(a2, r2, h);
        h = __builtin_fmaf(a3, r3, h);
        const float part = V * h;
        float ps = part + qperm<XOR1>(part);
        ps = ps + qperm<XOR2>(ps);
        // sigmoid (duplicated on quad)
        const float dE = fexp2(__builtin_fmaf(ps, -L2E, sigBias));
        const float delta = frcp(1.0f + dE);
        // own tanh at V (lanes 0,1: x-side; lanes 2,3: at F, Taylor base)
        const float tE = fexp2(__builtin_fmaf(T2L, V, shiftc));
        const float th = __builtin_fmaf(-2.0f, frcp(tE + 1.0f), 1.0f);
        const float s  = __builtin_fmaf(-th, th, 1.0f);   // sech^2
        // u = K.F + delta * K.(X - F); both reduces hide under sigmoid latency
        const float Dl = r2 - F;                  // lanes 2,3: x_partner - F
        const float tF = cKn * F;
        const float tD = cKn * Dl;
        float kF = tF + qperm<XOR1>(tF); kF = kF + qperm<XOR2>(kF);
        float kD = tD + qperm<XOR1>(tD); kD = kD + qperm<XOR2>(kD);
        const float un = __builtin_fmaf(delta, kD, kF);
        if (acc) {
            SXX = __builtin_fmaf(V, V, SXX);
            SXY = __builtin_fmaf(V, r1, SXY);
            SD += delta;
        }
        // xhat update + Taylor-corrected tanh(NH) = tanh(F + d)
        const float d   = delta * Dl;
        const float NH  = F + d;
        const float c2t = __builtin_fmaf(-d, th, 1.0f);
        const float c1t = d * s;
        const float th_eff = __builtin_fmaf(c1t, c2t, th);
        const float TPx = qperm<XOR1>(th);        // lanes 0,1: partner x-tanh
        TPin = qperm<XOR1>(th_eff);               // lanes 2,3: partner xhat-tanh
        // x update (lanes 0,1); lanes 2,3 compute junk that the select discards
        const float cwv = wi + cwc;
        const float Rr  = __builtin_fmaf(Acf, St, __builtin_fmaf(cTf, TPx, cwv));
        const float Xn  = __builtin_fmaf(cUf, un, Rr);
        St = hi ? NH : Xn;
        U  = un;
    };

    // t = 1
    step(w_1, true);

    // t = 2 .. 2045: 511 groups of 4; unroll-2 role-swapped double buffer.
    float c0 = rw[2], c1 = rw[3], c2 = rw[4], c3 = rw[5];
    const float* p = rw + 6;
    for (int k = 0; k < 255; ++k) {
        const float n0 = p[0], n1 = p[1], n2 = p[2], n3 = p[3];
        step(c0, true); step(c1, true); step(c2, true); step(c3, true);
        c0 = p[4]; c1 = p[5]; c2 = p[6]; c3 = p[7];
        step(n0, true); step(n1, true); step(n2, true); step(n3, true);
        p += 8;
    }
    step(c0, true); step(c1, true); step(c2, true); step(c3, true);

    // t = 2046: final step, no stage accumulation
    step(w_T, false);

    // epilogue: out = (Sx1x1+Sx2x2) + (K'SK quadratic) + SD + 10*|x_T|^2
    const float xx    = St * St;              // x_T^2 components on lanes 0,1
    const float sxx_p = qperm<XOR1>(SXX);     // lane0 <- lane1's sum x2^2
    const float xx_s  = xx + qperm<XOR1>(xx); // lane0: x1_T^2 + x2_T^2
    const float suu   = K0 * K0 * SXX + 2.0f * K0 * K1 * SXY + K1 * K1 * sxx_p;
    const float res   = (SXX + sxx_p) + suu + SD + 10.0f * xx_s;
    if (q == 0) out[b] = res;
}

extern "C" void kernel_launch(void* const* d_in, const int* in_sizes, int n_in,
                              void* d_out, int out_size, void* d_ws, size_t ws_size,
                              hipStream_t stream) {
    const float* w  = (const float*)d_in[0];
    const float* K  = (const float*)d_in[1];
    const float* L  = (const float*)d_in[2];
    const float* M  = (const float*)d_in[3];
    const float* Mo = (const float*)d_in[4];
    float* out = (float*)d_out;
    cstr_kernel<<<dim3(4 * NB / 64), dim3(64), 0, stream>>>(w, K, L, M, Mo, out);
}